// Round 11
// baseline (260.305 us; speedup 1.0000x reference)
//
#include <hip/hip_runtime.h>
#include <hip/hip_bf16.h>

#define S_LEN 4096
#define DIM   1024
#define NH    16
#define HD    64

typedef unsigned short u16;
typedef short  bf16x8 __attribute__((ext_vector_type(8)));
typedef float  f32x4  __attribute__((ext_vector_type(4)));

__device__ __forceinline__ u16 f2bf(float f){
  union { float f; unsigned u; } x; x.f = f;
  unsigned u = x.u;
  return (u16)((u + 0x7FFFu + ((u >> 16) & 1u)) >> 16);
}
__device__ __forceinline__ unsigned pk2(float a, float b){
  union { __hip_bfloat162 h; unsigned u; } x;
  x.h = __float22bfloat162_rn(float2{a, b});
  return x.u;
}
// async global->LDS, 16B per lane (dest must be wave-uniform base + lane*16)
__device__ __forceinline__ void ld2lds16(const u16* g, u16* l){
  __builtin_amdgcn_global_load_lds((const __attribute__((address_space(1))) void*)g,
                                   (__attribute__((address_space(3))) void*)l, 16, 0, 0);
}

// Q pre-scale: 1/sqrt(64) * log2(e)  (softmax done in exp2 domain)
#define QSCALE 0.1803368801111204f

__global__ __launch_bounds__(256) void fill_sentinel(float* __restrict__ out, int n){
  int i = blockIdx.x * 256 + threadIdx.x;
  if (i < n) out[i] = 77.0f;
}

// ---------------- X fp32 -> bf16 (one-time) ----------------
__global__ __launch_bounds__(256) void conv_x(const float* __restrict__ X, u16* __restrict__ Xb){
  size_t i = ((size_t)blockIdx.x * 256 + threadIdx.x) * 8;
  float4 v0 = *(const float4*)(X + i);
  float4 v1 = *(const float4*)(X + i + 4);
  uint4 w;
  w.x = pk2(v0.x, v0.y); w.y = pk2(v0.z, v0.w);
  w.z = pk2(v1.x, v1.y); w.w = pk2(v1.z, v1.w);
  *(uint4*)(Xb + i) = w;
}

// ---------------- W fp32 [k][n] -> Wt bf16 [z][n][k] ----------------
__global__ __launch_bounds__(256) void transpose_w(
    const float* __restrict__ W0, const float* __restrict__ W1, const float* __restrict__ W2,
    u16* __restrict__ Wt)
{
  const float* W = blockIdx.z==0 ? W0 : blockIdx.z==1 ? W1 : W2;
  u16* T = Wt + (size_t)blockIdx.z * DIM * DIM;
  __shared__ __align__(16) u16 tile[64*72];
  int k0 = blockIdx.x*64, n0 = blockIdx.y*64;
  int t = threadIdx.x;
  #pragma unroll
  for (int i = 0; i < 4; ++i){
    int idx = t + i*256;
    int row = idx >> 4, col4 = (idx & 15) * 4;
    float4 v = *(const float4*)(W + (size_t)(k0+row)*DIM + n0 + col4);
    tile[(col4+0)*72 + row] = f2bf(v.x);
    tile[(col4+1)*72 + row] = f2bf(v.y);
    tile[(col4+2)*72 + row] = f2bf(v.z);
    tile[(col4+3)*72 + row] = f2bf(v.w);
  }
  __syncthreads();
  #pragma unroll
  for (int i = 0; i < 2; ++i){
    int idx = t + i*256;
    int n = idx >> 3, k16 = (idx & 7) * 8;
    *(int4*)(T + (size_t)(n0+n)*DIM + k0 + k16) = *(const int4*)(tile + n*72 + k16);
  }
}

// ---------------- shared epilogue: C-frags -> Q / Kf / Vf ----------------
__device__ __forceinline__ void qkv_epilogue(
    int z, int m0, int n0, int wm, int wn, int quad, int l15,
    const f32x4 acc[4][4], const float* bias,
    u16* __restrict__ qb, u16* __restrict__ kf_out, u16* __restrict__ vf_out)
{
  #pragma unroll
  for (int nt=0; nt<4; ++nt){
    int n = n0 + wn + nt*16 + l15;
    float bv = bias[n];
    int h = n >> 6, d = n & 63;
    #pragma unroll
    for (int mt=0; mt<4; ++mt){
      int mb = m0 + wm + mt*16 + quad*4;   // C/D: row=quad*4+reg, col=l15
      f32x4 c = acc[mt][nt];
      if (z == 0){
        #pragma unroll
        for (int r=0; r<4; ++r)
          qb[(size_t)(mb + r)*DIM + n] = f2bf((c[r] + bv) * QSCALE);
      } else if (z == 1){
        int half = d >> 5, quadk = (d >> 3) & 3, j = d & 7;
        #pragma unroll
        for (int r=0; r<4; ++r){
          int s = mb + r;
          size_t idx = ((((size_t)h*256 + (s >> 4))*2 + half)*64 + quadk*16 + (s & 15))*8 + j;
          kf_out[idx] = f2bf(c[r] + bv);
        }
      } else {
        int kt64 = mb >> 6, c2 = (mb >> 5) & 1, quadv = (mb >> 3) & 3, j0 = mb & 7;
        int dt = d >> 4, l15v = d & 15;
        size_t base = (((((size_t)h*64 + kt64)*4 + dt)*2 + c2)*64 + quadv*16 + l15v)*8 + j0;
        ushort4 p;
        p.x = f2bf(c[0]+bv); p.y = f2bf(c[1]+bv);
        p.z = f2bf(c[2]+bv); p.w = f2bf(c[3]+bv);
        *(ushort4*)(vf_out + base) = p;
      }
    }
  }
}

// ---------------- fast QKV GEMM: bf16 in, global_load_lds staging ----------------
__global__ __launch_bounds__(256) void qkv_gemm_fast(
    const u16* __restrict__ Xbf, const u16* __restrict__ Wt,
    const float* __restrict__ b0, const float* __restrict__ b1, const float* __restrict__ b2,
    u16* __restrict__ qb, u16* __restrict__ kf_out, u16* __restrict__ vf_out)
{
  int z = blockIdx.z;
  const u16* Wz = Wt + (size_t)z * DIM * DIM;
  const float* bias = z==0 ? b0 : z==1 ? b1 : b2;

  __shared__ __align__(16) u16 As[128*32];
  __shared__ __align__(16) u16 Bs[128*32];

  int m0 = blockIdx.x * 128, n0 = blockIdx.y * 128;
  int t = threadIdx.x, wave = t >> 6, lane = t & 63, quad = lane >> 4, l15 = lane & 15;
  int wm = (wave >> 1) * 64, wn = (wave & 1) * 64;

  f32x4 acc[4][4];
  #pragma unroll
  for (int i=0;i<4;++i)
    #pragma unroll
    for (int j=0;j<4;++j) acc[i][j] = (f32x4){0.f,0.f,0.f,0.f};

  int srow = wave*32 + (lane >> 2);
  int skc  = (lane & 3) * 8;
  const u16* gA0 = Xbf + (size_t)(m0 + srow)*DIM + skc;
  const u16* gA1 = gA0 + (size_t)16*DIM;
  const u16* gB0 = Wz  + (size_t)(n0 + srow)*DIM + skc;
  const u16* gB1 = gB0 + (size_t)16*DIM;
  u16* lA0 = As + srow*32 + skc;
  u16* lA1 = lA0 + 16*32;
  u16* lB0 = Bs + srow*32 + skc;
  u16* lB1 = lB0 + 16*32;

  for (int kt = 0; kt < 32; ++kt){
    int ko = kt * 32;
    __syncthreads();
    ld2lds16(gA0 + ko, lA0);
    ld2lds16(gA1 + ko, lA1);
    ld2lds16(gB0 + ko, lB0);
    ld2lds16(gB1 + ko, lB1);
    __syncthreads();
    bf16x8 af[4], bfr[4];
    #pragma unroll
    for (int mt=0; mt<4; ++mt) af[mt]  = *(const bf16x8*)(As + (wm + mt*16 + l15)*32 + quad*8);
    #pragma unroll
    for (int nt=0; nt<4; ++nt) bfr[nt] = *(const bf16x8*)(Bs + (wn + nt*16 + l15)*32 + quad*8);
    #pragma unroll
    for (int mt=0; mt<4; ++mt)
      #pragma unroll
      for (int nt=0; nt<4; ++nt)
        acc[mt][nt] = __builtin_amdgcn_mfma_f32_16x16x32_bf16(af[mt], bfr[nt], acc[mt][nt], 0, 0, 0);
  }
  qkv_epilogue(z, m0, n0, wm, wn, quad, l15, acc, bias, qb, kf_out, vf_out);
}

// ---------------- legacy QKV GEMM (fp32 in; used when ws < 38 MB) ----------------
__global__ __launch_bounds__(256) void qkv_gemm_legacy(
    const float* __restrict__ X,
    const float* __restrict__ Wq, const float* __restrict__ Wk, const float* __restrict__ Wv,
    const float* __restrict__ b0, const float* __restrict__ b1, const float* __restrict__ b2,
    u16* __restrict__ qb, u16* __restrict__ kf_out, u16* __restrict__ vf_out)
{
  int z = blockIdx.z;
  const float* W    = z==0 ? Wq : z==1 ? Wk : Wv;
  const float* bias = z==0 ? b0 : z==1 ? b1 : b2;

  __shared__ __align__(16) u16 As[128*40];
  __shared__ __align__(16) u16 Bs[128*40];

  int m0 = blockIdx.x * 128, n0 = blockIdx.y * 128;
  int t = threadIdx.x, wave = t >> 6, lane = t & 63, quad = lane >> 4, l15 = lane & 15;
  int wm = (wave >> 1) * 64, wn = (wave & 1) * 64;

  f32x4 acc[4][4];
  #pragma unroll
  for (int i=0;i<4;++i)
    #pragma unroll
    for (int j=0;j<4;++j) acc[i][j] = (f32x4){0.f,0.f,0.f,0.f};

  int sr = t >> 2, sc = (t & 3) * 8;
  const float* gA0 = X + (size_t)(m0 + sr) * DIM + sc;
  const float* gA1 = X + (size_t)(m0 + 64 + sr) * DIM + sc;
  int br = t >> 3, bc = (t & 7) * 16;
  const float* gW = W + (size_t)br * DIM + n0 + bc;

  for (int kt = 0; kt < 32; ++kt){
    int ko = kt * 32;
    float4 a00 = *(const float4*)(gA0 + ko);
    float4 a01 = *(const float4*)(gA0 + ko + 4);
    float4 a10 = *(const float4*)(gA1 + ko);
    float4 a11 = *(const float4*)(gA1 + ko + 4);
    float4 w0  = *(const float4*)(gW + (size_t)ko*DIM);
    float4 w1  = *(const float4*)(gW + (size_t)ko*DIM + 4);
    float4 w2  = *(const float4*)(gW + (size_t)ko*DIM + 8);
    float4 w3  = *(const float4*)(gW + (size_t)ko*DIM + 12);
    int4 pa0, pa1;
    pa0.x = pk2(a00.x,a00.y); pa0.y = pk2(a00.z,a00.w);
    pa0.z = pk2(a01.x,a01.y); pa0.w = pk2(a01.z,a01.w);
    pa1.x = pk2(a10.x,a10.y); pa1.y = pk2(a10.z,a10.w);
    pa1.z = pk2(a11.x,a11.y); pa1.w = pk2(a11.z,a11.w);
    u16 wb[16];
    wb[0]=f2bf(w0.x); wb[1]=f2bf(w0.y); wb[2]=f2bf(w0.z); wb[3]=f2bf(w0.w);
    wb[4]=f2bf(w1.x); wb[5]=f2bf(w1.y); wb[6]=f2bf(w1.z); wb[7]=f2bf(w1.w);
    wb[8]=f2bf(w2.x); wb[9]=f2bf(w2.y); wb[10]=f2bf(w2.z); wb[11]=f2bf(w2.w);
    wb[12]=f2bf(w3.x); wb[13]=f2bf(w3.y); wb[14]=f2bf(w3.z); wb[15]=f2bf(w3.w);
    __syncthreads();
    *(int4*)(As + sr*40 + sc)      = pa0;
    *(int4*)(As + (64+sr)*40 + sc) = pa1;
    #pragma unroll
    for (int j=0;j<16;++j) Bs[(bc+j)*40 + br] = wb[j];
    __syncthreads();
    bf16x8 af[4], bfr[4];
    #pragma unroll
    for (int mt=0; mt<4; ++mt) af[mt]  = *(const bf16x8*)(As + (wm + mt*16 + l15)*40 + quad*8);
    #pragma unroll
    for (int nt=0; nt<4; ++nt) bfr[nt] = *(const bf16x8*)(Bs + (wn + nt*16 + l15)*40 + quad*8);
    #pragma unroll
    for (int mt=0; mt<4; ++mt)
      #pragma unroll
      for (int nt=0; nt<4; ++nt)
        acc[mt][nt] = __builtin_amdgcn_mfma_f32_16x16x32_bf16(af[mt], bfr[nt], acc[mt][nt], 0, 0, 0);
  }
  qkv_epilogue(z, m0, n0, wm, wn, quad, l15, acc, bias, qb, kf_out, vf_out);
}

// ---------------- flash attention: LDS-shared K/V, double-buffered ----------------
// grid (32, 16), 256 threads = 4 waves; wave owns 32 queries (2 subtiles).
// Each kt tile (64 keys): 16 KB K+V frags staged ONCE per block into LDS via
// global_load_lds (prefetch next while computing current), all 4 waves read
// from LDS -> L1 demand /4 vs per-wave-private streams (R8's 64 B/cyc wall).
// lsum computed by MFMA with a ones-row A-fragment (row0=1): l = 1^T P^T.
#define PSTR 72
__global__ __launch_bounds__(256) void attn(
    const u16* __restrict__ Qb, const u16* __restrict__ Kf,
    const u16* __restrict__ Vf, float* __restrict__ out)
{
  int h = blockIdx.y;
  int t = threadIdx.x, wave = t >> 6, lane = t & 63, quad = lane >> 4, l15 = lane & 15;
  int q0 = blockIdx.x * 128 + wave * 32;

  __shared__ __align__(16) u16 KV[2][16*512];   // 2 x 16KB: groups 0-7 K, 8-15 V
  __shared__ __align__(16) u16 Ps[4*16*PSTR];   // 9 KB per-wave P buffers
  u16* Pw = Ps + wave * (16*PSTR);

  const u16* Kfh = Kf + (size_t)h * 262144;
  const u16* Vfh = Vf + (size_t)h * 262144;

  // ones A-fragment: row m=0 (lanes with l15==0) = 1.0 bf16
  short ov = (l15 == 0) ? (short)0x3F80 : (short)0;
  bf16x8 a_one = (bf16x8){ov,ov,ov,ov,ov,ov,ov,ov};

  bf16x8 qf[2][2];
  #pragma unroll
  for (int qs=0; qs<2; ++qs){
    const u16* Qp = Qb + (size_t)(q0 + qs*16 + l15)*DIM + h*HD;
    qf[qs][0] = *(const bf16x8*)(Qp + quad*8);
    qf[qs][1] = *(const bf16x8*)(Qp + 32 + quad*8);
  }

  f32x4 O[2][4];
  #pragma unroll
  for (int qs=0; qs<2; ++qs)
    #pragma unroll
    for (int dt=0; dt<4; ++dt) O[qs][dt] = (f32x4){0.f,0.f,0.f,0.f};
  f32x4 lacc[2] = {(f32x4){0.f,0.f,0.f,0.f}, (f32x4){0.f,0.f,0.f,0.f}};

  // stage tile kt into KV[buf]: thread handles groups {wave, wave+4, wave+8, wave+12}
  #define STAGE(kt_, buf_)                                                         \
    {                                                                              \
      int kt8 = (kt_) * 8;                                                         \
      _Pragma("unroll")                                                            \
      for (int c = 0; c < 4; ++c){                                                 \
        int g = wave + c*4;                                                        \
        const u16* src = (g < 8) ? (Kfh + (size_t)(kt8 + g)*512 + lane*8)          \
                                 : (Vfh + (size_t)(kt8 + g - 8)*512 + lane*8);     \
        ld2lds16(src, &KV[buf_][g*512 + lane*8]);                                  \
      }                                                                            \
    }

  STAGE(0, 0);
  __syncthreads();

  for (int kt = 0; kt < 64; ++kt){
    int buf = kt & 1;
    if (kt + 1 < 64) STAGE(kt + 1, buf ^ 1);

    const u16* kvb = KV[buf];
    bf16x8 kfr[4][2], vfr[4][2];
    #pragma unroll
    for (int kn=0; kn<4; ++kn)
      #pragma unroll
      for (int hf=0; hf<2; ++hf)
        kfr[kn][hf] = *(const bf16x8*)(kvb + (kn*2 + hf)*512 + lane*8);
    #pragma unroll
    for (int dt=0; dt<4; ++dt)
      #pragma unroll
      for (int c2=0; c2<2; ++c2)
        vfr[dt][c2] = *(const bf16x8*)(kvb + (8 + dt*2 + c2)*512 + lane*8);

    #pragma unroll
    for (int qs=0; qs<2; ++qs){
      f32x4 st[4];
      #pragma unroll
      for (int kn=0; kn<4; ++kn){
        f32x4 zz = (f32x4){0.f,0.f,0.f,0.f};
        zz = __builtin_amdgcn_mfma_f32_16x16x32_bf16(kfr[kn][0], qf[qs][0], zz, 0,0,0);
        zz = __builtin_amdgcn_mfma_f32_16x16x32_bf16(kfr[kn][1], qf[qs][1], zz, 0,0,0);
        st[kn] = zz;
      }
      // scores in log2 domain (Q pre-scaled by log2e/8): p = 2^s
      #pragma unroll
      for (int kn=0; kn<4; ++kn)
        #pragma unroll
        for (int r=0; r<4; ++r)
          st[kn][r] = exp2f(st[kn][r]);
      __builtin_amdgcn_wave_barrier();
      #pragma unroll
      for (int kn=0; kn<4; ++kn){
        uint2 w;
        w.x = pk2(st[kn][0], st[kn][1]);
        w.y = pk2(st[kn][2], st[kn][3]);
        *(uint2*)(Pw + l15*PSTR + kn*16 + quad*4) = w;
      }
      __builtin_amdgcn_wave_barrier();
      bf16x8 pf0 = *(const bf16x8*)(Pw + l15*PSTR + quad*8);
      bf16x8 pf1 = *(const bf16x8*)(Pw + l15*PSTR + 32 + quad*8);
      __builtin_amdgcn_wave_barrier();
      // l = 1^T P^T via MFMA (row 0 only) -- replaces 16 VALU adds
      lacc[qs] = __builtin_amdgcn_mfma_f32_16x16x32_bf16(a_one, pf0, lacc[qs], 0,0,0);
      lacc[qs] = __builtin_amdgcn_mfma_f32_16x16x32_bf16(a_one, pf1, lacc[qs], 0,0,0);
      #pragma unroll
      for (int dt=0; dt<4; ++dt){
        f32x4 o = O[qs][dt];
        o = __builtin_amdgcn_mfma_f32_16x16x32_bf16(vfr[dt][0], pf0, o, 0,0,0);
        o = __builtin_amdgcn_mfma_f32_16x16x32_bf16(vfr[dt][1], pf1, o, 0,0,0);
        O[qs][dt] = o;
      }
    }
    __syncthreads();   // all waves done with buf; next tile staged into buf^1
  }

  // epilogue: l sits in D row 0 = lane(quad0, l15).reg0; broadcast across quads
  #pragma unroll
  for (int qs=0; qs<2; ++qs){
    float l = __shfl(lacc[qs][0], l15, 64);   // lane l15 == (quad0, l15)
    float inv = 1.0f / l;
    int query = q0 + qs*16 + l15;
    #pragma unroll
    for (int dt=0; dt<4; ++dt){
      float4 v;
      v.x = O[qs][dt][0]*inv; v.y = O[qs][dt][1]*inv;
      v.z = O[qs][dt][2]*inv; v.w = O[qs][dt][3]*inv;
      *(float4*)(out + (size_t)query*DIM + h*HD + dt*16 + quad*4) = v;
    }
  }
}

extern "C" void kernel_launch(void* const* d_in, const int* in_sizes, int n_in,
                              void* d_out, int out_size, void* d_ws, size_t ws_size,
                              hipStream_t stream)
{
  const float* X  = (const float*)d_in[0];
  const float* Wq = (const float*)d_in[1];
  const float* bq = (const float*)d_in[2];
  const float* Wk = (const float*)d_in[3];
  const float* bk = (const float*)d_in[4];
  const float* Wv = (const float*)d_in[5];
  const float* bv = (const float*)d_in[6];
  float* out = (float*)d_out;
  u16*   ws  = (u16*)d_ws;

  const size_t SD = (size_t)S_LEN * DIM;
  const size_t need_fast = (4*SD + 3*(size_t)DIM*DIM) * sizeof(u16);  // ~38 MB
  const size_t need_min  = (size_t)24 * 1024 * 1024;

  if (ws_size >= need_fast){
    u16* xbf = ws;
    u16* wt  = xbf + SD;
    u16* qb  = wt + 3*(size_t)DIM*DIM;
    u16* kf  = qb + SD;
    u16* vf  = kf + SD;
    conv_x       <<<dim3((int)(SD/8/256)), 256, 0, stream>>>(X, xbf);
    transpose_w  <<<dim3(16,16,3), 256, 0, stream>>>(Wq, Wk, Wv, wt);
    qkv_gemm_fast<<<dim3(32, 8, 3), 256, 0, stream>>>(xbf, wt, bq, bk, bv, qb, kf, vf);
    attn         <<<dim3(32, 16   ), 256, 0, stream>>>(qb, kf, vf, out);
  } else if (ws_size >= need_min){
    u16* qb = ws;
    u16* kf = qb + SD;
    u16* vf = kf + SD;
    qkv_gemm_legacy<<<dim3(32, 8, 3), 256, 0, stream>>>(X, Wq, Wk, Wv, bq, bk, bv, qb, kf, vf);
    attn           <<<dim3(32, 16   ), 256, 0, stream>>>(qb, kf, vf, out);
  } else {
    fill_sentinel<<<(out_size + 255)/256, 256, 0, stream>>>(out, out_size);
  }
}

// Round 12
// 217.643 us; speedup vs baseline: 1.1960x; 1.1960x over previous
//
#include <hip/hip_runtime.h>
#include <hip/hip_bf16.h>

#define S_LEN 4096
#define DIM   1024
#define NH    16
#define HD    64

typedef unsigned short u16;
typedef short  bf16x8 __attribute__((ext_vector_type(8)));
typedef float  f32x4  __attribute__((ext_vector_type(4)));

__device__ __forceinline__ u16 f2bf(float f){
  union { float f; unsigned u; } x; x.f = f;
  unsigned u = x.u;
  return (u16)((u + 0x7FFFu + ((u >> 16) & 1u)) >> 16);
}
__device__ __forceinline__ unsigned pk2(float a, float b){
  union { __hip_bfloat162 h; unsigned u; } x;
  x.h = __float22bfloat162_rn(float2{a, b});
  return x.u;
}
// async global->LDS, 16B per lane (dest must be wave-uniform base + lane*16)
__device__ __forceinline__ void ld2lds16(const u16* g, u16* l){
  __builtin_amdgcn_global_load_lds((const __attribute__((address_space(1))) void*)g,
                                   (__attribute__((address_space(3))) void*)l, 16, 0, 0);
}

// Q pre-scale: 1/sqrt(64) * log2(e)  (softmax in exp2 domain; v_exp_f32 = 2^x)
#define QSCALE 0.1803368801111204f

__global__ __launch_bounds__(256) void fill_sentinel(float* __restrict__ out, int n){
  int i = blockIdx.x * 256 + threadIdx.x;
  if (i < n) out[i] = 77.0f;
}

// ---------------- X fp32 -> bf16 (one-time) ----------------
__global__ __launch_bounds__(256) void conv_x(const float* __restrict__ X, u16* __restrict__ Xb){
  size_t i = ((size_t)blockIdx.x * 256 + threadIdx.x) * 8;
  float4 v0 = *(const float4*)(X + i);
  float4 v1 = *(const float4*)(X + i + 4);
  uint4 w;
  w.x = pk2(v0.x, v0.y); w.y = pk2(v0.z, v0.w);
  w.z = pk2(v1.x, v1.y); w.w = pk2(v1.z, v1.w);
  *(uint4*)(Xb + i) = w;
}

// ---------------- W fp32 [k][n] -> Wt bf16 [z][n][k] ----------------
__global__ __launch_bounds__(256) void transpose_w(
    const float* __restrict__ W0, const float* __restrict__ W1, const float* __restrict__ W2,
    u16* __restrict__ Wt)
{
  const float* W = blockIdx.z==0 ? W0 : blockIdx.z==1 ? W1 : W2;
  u16* T = Wt + (size_t)blockIdx.z * DIM * DIM;
  __shared__ __align__(16) u16 tile[64*72];
  int k0 = blockIdx.x*64, n0 = blockIdx.y*64;
  int t = threadIdx.x;
  #pragma unroll
  for (int i = 0; i < 4; ++i){
    int idx = t + i*256;
    int row = idx >> 4, col4 = (idx & 15) * 4;
    float4 v = *(const float4*)(W + (size_t)(k0+row)*DIM + n0 + col4);
    tile[(col4+0)*72 + row] = f2bf(v.x);
    tile[(col4+1)*72 + row] = f2bf(v.y);
    tile[(col4+2)*72 + row] = f2bf(v.z);
    tile[(col4+3)*72 + row] = f2bf(v.w);
  }
  __syncthreads();
  #pragma unroll
  for (int i = 0; i < 2; ++i){
    int idx = t + i*256;
    int n = idx >> 3, k16 = (idx & 7) * 8;
    *(int4*)(T + (size_t)(n0+n)*DIM + k0 + k16) = *(const int4*)(tile + n*72 + k16);
  }
}

// ---------------- shared epilogue: C-frags -> Q / Kf / Vf ----------------
__device__ __forceinline__ void qkv_epilogue(
    int z, int m0, int n0, int wm, int wn, int quad, int l15,
    const f32x4 acc[4][4], const float* bias,
    u16* __restrict__ qb, u16* __restrict__ kf_out, u16* __restrict__ vf_out)
{
  #pragma unroll
  for (int nt=0; nt<4; ++nt){
    int n = n0 + wn + nt*16 + l15;
    float bv = bias[n];
    int h = n >> 6, d = n & 63;
    #pragma unroll
    for (int mt=0; mt<4; ++mt){
      int mb = m0 + wm + mt*16 + quad*4;   // C/D: row=quad*4+reg, col=l15
      f32x4 c = acc[mt][nt];
      if (z == 0){
        #pragma unroll
        for (int r=0; r<4; ++r)
          qb[(size_t)(mb + r)*DIM + n] = f2bf((c[r] + bv) * QSCALE);
      } else if (z == 1){
        int half = d >> 5, quadk = (d >> 3) & 3, j = d & 7;
        #pragma unroll
        for (int r=0; r<4; ++r){
          int s = mb + r;
          size_t idx = ((((size_t)h*256 + (s >> 4))*2 + half)*64 + quadk*16 + (s & 15))*8 + j;
          kf_out[idx] = f2bf(c[r] + bv);
        }
      } else {
        int kt64 = mb >> 6, c2 = (mb >> 5) & 1, quadv = (mb >> 3) & 3, j0 = mb & 7;
        int dt = d >> 4, l15v = d & 15;
        size_t base = (((((size_t)h*64 + kt64)*4 + dt)*2 + c2)*64 + quadv*16 + l15v)*8 + j0;
        ushort4 p;
        p.x = f2bf(c[0]+bv); p.y = f2bf(c[1]+bv);
        p.z = f2bf(c[2]+bv); p.w = f2bf(c[3]+bv);
        *(ushort4*)(vf_out + base) = p;
      }
    }
  }
}

// ---------------- fast QKV GEMM: bf16 in, global_load_lds staging ----------------
__global__ __launch_bounds__(256) void qkv_gemm_fast(
    const u16* __restrict__ Xbf, const u16* __restrict__ Wt,
    const float* __restrict__ b0, const float* __restrict__ b1, const float* __restrict__ b2,
    u16* __restrict__ qb, u16* __restrict__ kf_out, u16* __restrict__ vf_out)
{
  int z = blockIdx.z;
  const u16* Wz = Wt + (size_t)z * DIM * DIM;
  const float* bias = z==0 ? b0 : z==1 ? b1 : b2;

  __shared__ __align__(16) u16 As[128*32];
  __shared__ __align__(16) u16 Bs[128*32];

  int m0 = blockIdx.x * 128, n0 = blockIdx.y * 128;
  int t = threadIdx.x, wave = t >> 6, lane = t & 63, quad = lane >> 4, l15 = lane & 15;
  int wm = (wave >> 1) * 64, wn = (wave & 1) * 64;

  f32x4 acc[4][4];
  #pragma unroll
  for (int i=0;i<4;++i)
    #pragma unroll
    for (int j=0;j<4;++j) acc[i][j] = (f32x4){0.f,0.f,0.f,0.f};

  int srow = wave*32 + (lane >> 2);
  int skc  = (lane & 3) * 8;
  const u16* gA0 = Xbf + (size_t)(m0 + srow)*DIM + skc;
  const u16* gA1 = gA0 + (size_t)16*DIM;
  const u16* gB0 = Wz  + (size_t)(n0 + srow)*DIM + skc;
  const u16* gB1 = gB0 + (size_t)16*DIM;
  u16* lA0 = As + srow*32 + skc;
  u16* lA1 = lA0 + 16*32;
  u16* lB0 = Bs + srow*32 + skc;
  u16* lB1 = lB0 + 16*32;

  for (int kt = 0; kt < 32; ++kt){
    int ko = kt * 32;
    __syncthreads();
    ld2lds16(gA0 + ko, lA0);
    ld2lds16(gA1 + ko, lA1);
    ld2lds16(gB0 + ko, lB0);
    ld2lds16(gB1 + ko, lB1);
    __syncthreads();
    bf16x8 af[4], bfr[4];
    #pragma unroll
    for (int mt=0; mt<4; ++mt) af[mt]  = *(const bf16x8*)(As + (wm + mt*16 + l15)*32 + quad*8);
    #pragma unroll
    for (int nt=0; nt<4; ++nt) bfr[nt] = *(const bf16x8*)(Bs + (wn + nt*16 + l15)*32 + quad*8);
    #pragma unroll
    for (int mt=0; mt<4; ++mt)
      #pragma unroll
      for (int nt=0; nt<4; ++nt)
        acc[mt][nt] = __builtin_amdgcn_mfma_f32_16x16x32_bf16(af[mt], bfr[nt], acc[mt][nt], 0, 0, 0);
  }
  qkv_epilogue(z, m0, n0, wm, wn, quad, l15, acc, bias, qb, kf_out, vf_out);
}

// ---------------- legacy QKV GEMM (fp32 in; used when ws < 38 MB) ----------------
__global__ __launch_bounds__(256) void qkv_gemm_legacy(
    const float* __restrict__ X,
    const float* __restrict__ Wq, const float* __restrict__ Wk, const float* __restrict__ Wv,
    const float* __restrict__ b0, const float* __restrict__ b1, const float* __restrict__ b2,
    u16* __restrict__ qb, u16* __restrict__ kf_out, u16* __restrict__ vf_out)
{
  int z = blockIdx.z;
  const float* W    = z==0 ? Wq : z==1 ? Wk : Wv;
  const float* bias = z==0 ? b0 : z==1 ? b1 : b2;

  __shared__ __align__(16) u16 As[128*40];
  __shared__ __align__(16) u16 Bs[128*40];

  int m0 = blockIdx.x * 128, n0 = blockIdx.y * 128;
  int t = threadIdx.x, wave = t >> 6, lane = t & 63, quad = lane >> 4, l15 = lane & 15;
  int wm = (wave >> 1) * 64, wn = (wave & 1) * 64;

  f32x4 acc[4][4];
  #pragma unroll
  for (int i=0;i<4;++i)
    #pragma unroll
    for (int j=0;j<4;++j) acc[i][j] = (f32x4){0.f,0.f,0.f,0.f};

  int sr = t >> 2, sc = (t & 3) * 8;
  const float* gA0 = X + (size_t)(m0 + sr) * DIM + sc;
  const float* gA1 = X + (size_t)(m0 + 64 + sr) * DIM + sc;
  int br = t >> 3, bc = (t & 7) * 16;
  const float* gW = W + (size_t)br * DIM + n0 + bc;

  for (int kt = 0; kt < 32; ++kt){
    int ko = kt * 32;
    float4 a00 = *(const float4*)(gA0 + ko);
    float4 a01 = *(const float4*)(gA0 + ko + 4);
    float4 a10 = *(const float4*)(gA1 + ko);
    float4 a11 = *(const float4*)(gA1 + ko + 4);
    float4 w0  = *(const float4*)(gW + (size_t)ko*DIM);
    float4 w1  = *(const float4*)(gW + (size_t)ko*DIM + 4);
    float4 w2  = *(const float4*)(gW + (size_t)ko*DIM + 8);
    float4 w3  = *(const float4*)(gW + (size_t)ko*DIM + 12);
    int4 pa0, pa1;
    pa0.x = pk2(a00.x,a00.y); pa0.y = pk2(a00.z,a00.w);
    pa0.z = pk2(a01.x,a01.y); pa0.w = pk2(a01.z,a01.w);
    pa1.x = pk2(a10.x,a10.y); pa1.y = pk2(a10.z,a10.w);
    pa1.z = pk2(a11.x,a11.y); pa1.w = pk2(a11.z,a11.w);
    u16 wb[16];
    wb[0]=f2bf(w0.x); wb[1]=f2bf(w0.y); wb[2]=f2bf(w0.z); wb[3]=f2bf(w0.w);
    wb[4]=f2bf(w1.x); wb[5]=f2bf(w1.y); wb[6]=f2bf(w1.z); wb[7]=f2bf(w1.w);
    wb[8]=f2bf(w2.x); wb[9]=f2bf(w2.y); wb[10]=f2bf(w2.z); wb[11]=f2bf(w2.w);
    wb[12]=f2bf(w3.x); wb[13]=f2bf(w3.y); wb[14]=f2bf(w3.z); wb[15]=f2bf(w3.w);
    __syncthreads();
    *(int4*)(As + sr*40 + sc)      = pa0;
    *(int4*)(As + (64+sr)*40 + sc) = pa1;
    #pragma unroll
    for (int j=0;j<16;++j) Bs[(bc+j)*40 + br] = wb[j];
    __syncthreads();
    bf16x8 af[4], bfr[4];
    #pragma unroll
    for (int mt=0; mt<4; ++mt) af[mt]  = *(const bf16x8*)(As + (wm + mt*16 + l15)*40 + quad*8);
    #pragma unroll
    for (int nt=0; nt<4; ++nt) bfr[nt] = *(const bf16x8*)(Bs + (wn + nt*16 + l15)*40 + quad*8);
    #pragma unroll
    for (int mt=0; mt<4; ++mt)
      #pragma unroll
      for (int nt=0; nt<4; ++nt)
        acc[mt][nt] = __builtin_amdgcn_mfma_f32_16x16x32_bf16(af[mt], bfr[nt], acc[mt][nt], 0, 0, 0);
  }
  qkv_epilogue(z, m0, n0, wm, wn, quad, l15, acc, bias, qb, kf_out, vf_out);
}

// ---------------- flash attention: R8 structure + native v_exp_f32 ----------------
// grid (32, 16), 256 threads = 4 waves; wave owns 32 queries (2 subtiles of 16).
// Private contiguous frag-layout K/V wave-loads (proven best, R8). Only change
// vs R8: p = __builtin_amdgcn_exp2f(s) with Q pre-scaled by log2e/8 — one raw
// v_exp_f32 per value (R8 had mul+exp; R10/R11's exp2f was a slow libcall).
#define PSTR 72
__global__ __launch_bounds__(256, 2) void attn(
    const u16* __restrict__ Qb, const u16* __restrict__ Kf,
    const u16* __restrict__ Vf, float* __restrict__ out)
{
  int h = blockIdx.y;
  int t = threadIdx.x, wave = t >> 6, lane = t & 63, quad = lane >> 4, l15 = lane & 15;
  int q0 = blockIdx.x * 128 + wave * 32;

  __shared__ __align__(16) u16 Ps[4*16*PSTR];
  u16* Pw = Ps + wave * (16*PSTR);

  const u16* Kfh = Kf + (size_t)h * 262144;
  const u16* Vfh = Vf + (size_t)h * 262144;

  bf16x8 qf[2][2];
  #pragma unroll
  for (int qs=0; qs<2; ++qs){
    const u16* Qp = Qb + (size_t)(q0 + qs*16 + l15)*DIM + h*HD;
    qf[qs][0] = *(const bf16x8*)(Qp + quad*8);
    qf[qs][1] = *(const bf16x8*)(Qp + 32 + quad*8);
  }

  f32x4 O[2][4];
  #pragma unroll
  for (int qs=0; qs<2; ++qs)
    #pragma unroll
    for (int dt=0; dt<4; ++dt) O[qs][dt] = (f32x4){0.f,0.f,0.f,0.f};
  float lsum[2] = {0.f, 0.f};

  for (int kt = 0; kt < 64; ++kt){
    bf16x8 kfr[4][2];
    #pragma unroll
    for (int kn=0; kn<4; ++kn)
      #pragma unroll
      for (int hf=0; hf<2; ++hf)
        kfr[kn][hf] = *(const bf16x8*)(Kfh + ((((size_t)kt*4 + kn)*2 + hf)*64 + lane)*8);
    bf16x8 vfr[4][2];
    #pragma unroll
    for (int dt=0; dt<4; ++dt)
      #pragma unroll
      for (int c2=0; c2<2; ++c2)
        vfr[dt][c2] = *(const bf16x8*)(Vfh + ((((size_t)kt*4 + dt)*2 + c2)*64 + lane)*8);

    #pragma unroll
    for (int qs=0; qs<2; ++qs){
      f32x4 st[4];
      #pragma unroll
      for (int kn=0; kn<4; ++kn){
        f32x4 zz = (f32x4){0.f,0.f,0.f,0.f};
        zz = __builtin_amdgcn_mfma_f32_16x16x32_bf16(kfr[kn][0], qf[qs][0], zz, 0,0,0);
        zz = __builtin_amdgcn_mfma_f32_16x16x32_bf16(kfr[kn][1], qf[qs][1], zz, 0,0,0);
        st[kn] = zz;
      }
      // scores in log2 domain: p = 2^s via raw v_exp_f32
      float ls = 0.f;
      #pragma unroll
      for (int kn=0; kn<4; ++kn)
        #pragma unroll
        for (int r=0; r<4; ++r){
          float p = __builtin_amdgcn_exp2f(st[kn][r]);
          st[kn][r] = p;
          ls += p;
        }
      lsum[qs] += ls;
      __builtin_amdgcn_wave_barrier();
      #pragma unroll
      for (int kn=0; kn<4; ++kn){
        uint2 w;
        w.x = pk2(st[kn][0], st[kn][1]);
        w.y = pk2(st[kn][2], st[kn][3]);
        *(uint2*)(Pw + l15*PSTR + kn*16 + quad*4) = w;
      }
      __builtin_amdgcn_wave_barrier();
      bf16x8 pf0 = *(const bf16x8*)(Pw + l15*PSTR + quad*8);
      bf16x8 pf1 = *(const bf16x8*)(Pw + l15*PSTR + 32 + quad*8);
      __builtin_amdgcn_wave_barrier();
      #pragma unroll
      for (int dt=0; dt<4; ++dt){
        f32x4 o = O[qs][dt];
        o = __builtin_amdgcn_mfma_f32_16x16x32_bf16(vfr[dt][0], pf0, o, 0,0,0);
        o = __builtin_amdgcn_mfma_f32_16x16x32_bf16(vfr[dt][1], pf1, o, 0,0,0);
        O[qs][dt] = o;
      }
    }
  }
  #pragma unroll
  for (int qs=0; qs<2; ++qs){
    float l = lsum[qs];
    l += __shfl_xor(l, 16, 64);
    l += __shfl_xor(l, 32, 64);
    float inv = 1.0f / l;
    int query = q0 + qs*16 + l15;
    #pragma unroll
    for (int dt=0; dt<4; ++dt){
      float4 v;
      v.x = O[qs][dt][0]*inv; v.y = O[qs][dt][1]*inv;
      v.z = O[qs][dt][2]*inv; v.w = O[qs][dt][3]*inv;
      *(float4*)(out + (size_t)query*DIM + h*HD + dt*16 + quad*4) = v;
    }
  }
}

extern "C" void kernel_launch(void* const* d_in, const int* in_sizes, int n_in,
                              void* d_out, int out_size, void* d_ws, size_t ws_size,
                              hipStream_t stream)
{
  const float* X  = (const float*)d_in[0];
  const float* Wq = (const float*)d_in[1];
  const float* bq = (const float*)d_in[2];
  const float* Wk = (const float*)d_in[3];
  const float* bk = (const float*)d_in[4];
  const float* Wv = (const float*)d_in[5];
  const float* bv = (const float*)d_in[6];
  float* out = (float*)d_out;
  u16*   ws  = (u16*)d_ws;

  const size_t SD = (size_t)S_LEN * DIM;
  const size_t need_fast = (4*SD + 3*(size_t)DIM*DIM) * sizeof(u16);  // ~38 MB
  const size_t need_min  = (size_t)24 * 1024 * 1024;

  if (ws_size >= need_fast){
    u16* xbf = ws;
    u16* wt  = xbf + SD;
    u16* qb  = wt + 3*(size_t)DIM*DIM;
    u16* kf  = qb + SD;
    u16* vf  = kf + SD;
    conv_x       <<<dim3((int)(SD/8/256)), 256, 0, stream>>>(X, xbf);
    transpose_w  <<<dim3(16,16,3), 256, 0, stream>>>(Wq, Wk, Wv, wt);
    qkv_gemm_fast<<<dim3(32, 8, 3), 256, 0, stream>>>(xbf, wt, bq, bk, bv, qb, kf, vf);
    attn         <<<dim3(32, 16   ), 256, 0, stream>>>(qb, kf, vf, out);
  } else if (ws_size >= need_min){
    u16* qb = ws;
    u16* kf = qb + SD;
    u16* vf = kf + SD;
    qkv_gemm_legacy<<<dim3(32, 8, 3), 256, 0, stream>>>(X, Wq, Wk, Wv, bq, bk, bv, qb, kf, vf);
    attn           <<<dim3(32, 16   ), 256, 0, stream>>>(qb, kf, vf, out);
  } else {
    fill_sentinel<<<(out_size + 255)/256, 256, 0, stream>>>(out, out_size);
  }
}